// Round 5
// baseline (107.384 us; speedup 1.0000x reference)
//
#include <hip/hip_runtime.h>
#include <math.h>

#define N_SAMPLES 131072
#define NUM_CLASSES 128
#define NB 64                 // bins (width 1/4 over s in [-14, 2])
#define MAX_FPR 0.7f          // 1 - RECALL_THRESHOLD
#define NBLK 512              // fused grid: 2 blocks/CU
#define ROWS_PER_BLK 256      // max per-bin count/block = 256 -> u16-safe
#define HP 33                 // class row pitch in LDS u32 words (32 + 1 pad)
// Partial layout per block: [0..4095] all-hist u16x2 (16 KB),
// [4096..6143] pos-hist u8x4 (8 KB). 24 KB/block -> 12.6 MB total.
#define PART_WORDS 6144

typedef unsigned int u32;

// bin(x; L) = floor((x - L + 14) * 4) clamped to [0,63]. Identical expression
// for the positive and the all histogram (same kernel, same registers).
__device__ __forceinline__ int bin_of(float x, float off /* (14-lse)*4 */) {
    int b = (int)__fmaf_rn(x, 4.0f, off);
    return min(max(b, 0), NB - 1);
}

// ---------------------------------------------------------------------------
// Fused phase 1 — UNCHANGED proven body (verified 102.9us round 4; main loop
// byte-identical to the 104.8us round-0 kernel). NB=64, two LDS hists, 34 KB
// LDS -> 2 blocks/CU, 256 rows/block, 16 lanes/row, 8 cols/lane via two
// coalesced float4 loads, 2-deep pipeline, 4 passes. Pos partial packed u8x4
// at writeout (12.6 MB total partials). Only change vs round 4: block 0
// zeroes ctrl[0..128] (doneCtr + 128 per-class pair tickets) instead of just
// doneCtr. NOTHING else in d_ws needs pre-zeroing (partials/ceArr/gHalf are
// fully overwritten with plain or agent stores before being read).
// ---------------------------------------------------------------------------
__global__ __launch_bounds__(1024, 8) void fused_kernel(
    const float* __restrict__ pred, const int* __restrict__ tgt,
    u32* __restrict__ part,      // [NBLK][6144]
    float* __restrict__ ceArr,   // [NBLK] plain-stored CE partials
    u32* __restrict__ ctrl)      // [129]: [0]=doneCtr, [1..128]=pairCtr
{
    __shared__ u32 hA[NUM_CLASSES * HP];   // all hist, u16x2  (16.9 KB)
    __shared__ u32 hP[NUM_CLASSES * HP];   // pos hist, u16x2  (16.9 KB)
    __shared__ float wsum[16];

    const int tid  = threadIdx.x;
    const int w    = tid >> 6;        // wave 0..15
    const int lane = tid & 63;
    const int j    = lane & 15;       // lane within row
    const int rs   = lane >> 4;       // row sub-index 0..3

    for (int i = tid; i < NUM_CLASSES * HP; i += 1024) { hA[i] = 0u; hP[i] = 0u; }
    if (blockIdx.x == 0 && tid < 129) ctrl[tid] = 0u;
    __syncthreads();

    const int rowBase = blockIdx.x * ROWS_PER_BLK + w * 4 + rs;
    float acc_lse = 0.0f, acc_xt = 0.0f, acc_sx = 0.0f;

    // 2-deep pipeline over 4 passes (row stride 64 per pass)
    const float* r0p = pred + (size_t)rowBase * 128;
    float4 a0 = *(const float4*)(r0p + j * 4);
    float4 a1 = *(const float4*)(r0p + 64 + j * 4);
    int    ta = tgt[rowBase];
    const float* r1p = r0p + (size_t)64 * 128;
    float4 c0 = *(const float4*)(r1p + j * 4);
    float4 c1 = *(const float4*)(r1p + 64 + j * 4);
    int    tb = tgt[rowBase + 64];

    #pragma unroll
    for (int p = 0; p < 4; p++) {
        float4 n0, n1; int tn = 0;
        if (p < 2) {
            const float* rn = pred + (size_t)(rowBase + (p + 2) * 64) * 128;
            n0 = *(const float4*)(rn + j * 4);
            n1 = *(const float4*)(rn + 64 + j * 4);
            tn = tgt[rowBase + (p + 2) * 64];
        }

        float e = __expf(a0.x) + __expf(a0.y) + __expf(a0.z) + __expf(a0.w)
                + __expf(a1.x) + __expf(a1.y) + __expf(a1.z) + __expf(a1.w);
        #pragma unroll
        for (int o = 1; o < 16; o <<= 1) e += __shfl_xor(e, o);
        const float lse = __logf(e);
        const float off = (14.0f - lse) * 4.0f;

        const float xv[8] = {a0.x, a0.y, a0.z, a0.w, a1.x, a1.y, a1.z, a1.w};
        #pragma unroll
        for (int q = 0; q < 8; q++) {
            const int c = (q < 4) ? (j * 4 + q) : (64 + j * 4 + (q - 4));
            const int b = bin_of(xv[q], off);
            const int word = ((b >> 1) + j) & 31;       // swizzle: 16 banks
            atomicAdd(&hA[c * HP + word], (b & 1) ? 65536u : 1u);
        }

        acc_sx  += (xv[0] + xv[1] + xv[2] + xv[3])
                 + (xv[4] + xv[5] + xv[6] + xv[7]);
        acc_lse += lse * 0.0625f;     // 16 lanes/row each add lse/16

        {   // exactly one of the row's 16 lanes owns the target column
            const int t = ta;
            float xt; bool hit = false;
            if ((t >> 2) == j)                        { xt = xv[t & 3];       hit = true; }
            else if (t >= 64 && ((t - 64) >> 2) == j) { xt = xv[4 + (t & 3)]; hit = true; }
            if (hit) {
                acc_xt += xt;
                const int bp = bin_of(xt, off);
                atomicAdd(&hP[t * HP + (((bp >> 1) + j) & 31)],
                          (bp & 1) ? 65536u : 1u);
            }
        }

        a0 = c0; a1 = c1; ta = tb;
        c0 = n0; c1 = n1; tb = tn;
    }

    // CE partial: sum(lse) - 0.9*sum(x_t) - (0.1/128)*sum(x)
    float ce = acc_lse - 0.9f * acc_xt - (0.1f / 128.0f) * acc_sx;
    #pragma unroll
    for (int o = 32; o; o >>= 1) ce += __shfl_xor(ce, o);
    if (lane == 0) wsum[w] = ce;
    __syncthreads();
    if (tid == 0) {
        float s = 0.0f;
        #pragma unroll
        for (int i = 0; i < 16; i++) s += wsum[i];
        ceArr[blockIdx.x] = s;       // plain store, no init needed
    }

    // un-rotating writeout. All-hist: linear i = c*32 + bw, u16x2 unchanged.
    u32* outp = part + (size_t)blockIdx.x * PART_WORDS;
    for (int i = tid; i < 4096; i += 1024) {
        const int c = i >> 5, bw = i & 31;
        const int src = c * HP + ((bw + ((c >> 2) & 15)) & 31);
        outp[i] = hA[src];
    }
    // Pos-hist: pack 4 bins/u32 (u8 each). Word w4 of class c covers bins
    // 4*w4 .. 4*w4+3, i.e. LDS u16x2 words (2*w4 + jc)&31 and (2*w4+1 + jc)&31.
    for (int i = tid; i < 2048; i += 1024) {
        const int c  = i >> 4, w4 = i & 15;
        const int jc = (c >> 2) & 15;
        const u32 lo = hP[c * HP + (((2 * w4)     + jc) & 31)]; // bins 4w4,4w4+1
        const u32 hi = hP[c * HP + (((2 * w4 + 1) + jc) & 31)]; // bins 4w4+2,+3
        const u32 b0 = min(lo & 0xffffu, 255u);
        const u32 b1 = min(lo >> 16,     255u);
        const u32 b2 = min(hi & 0xffffu, 255u);
        const u32 b3 = min(hi >> 16,     255u);
        outp[4096 + i] = b0 | (b1 << 8) | (b2 << 16) | (b3 << 24);
    }
}

// ---------------------------------------------------------------------------
// Reducer + finalize, SPLIT-HALF version: 256 blocks (all 256 CUs active,
// was 128) x 1024 threads. Block b: class k = b&127, half h = b>>7 sums
// partials [h*256, h*256+256) — thread t: word w=t&31, slice sl=t>>5 covers
// 8 partials (coalesced, 8-deep MLP). LDS-atomic merge into 64 u32 bins,
// then pair rendezvous:
//  - both blocks publish their 128-word half-sum via AGENT-scope stores
//    (cross-XCD safe: dispatch->XCD mapping undefined, per-XCD L2s not
//    coherent) into their OWN gHalf slot (no races, no pre-zeroing),
//  - __syncthreads (drains each thread's stores) -> thread 0 __threadfence
//    -> atomicAdd(pairCtr[k]) ticket (the pattern already harness-proven
//    for doneCtr/paucArr in rounds 0/1/4),
//  - first arriver exits; second merges the other half via agent loads with
//    its own LDS copy (integer adds -> bitwise-identical bins) and runs the
//    UNCHANGED scan + clipped trapezoidal pAUC + doneCtr finalize.
// Atomics added: 256 pair tickets + 128 done tickets — nowhere near the
// round-1 2M-atomic op-rate wall.
// ---------------------------------------------------------------------------
__global__ __launch_bounds__(1024) void pauc_reduce(
    const u32* __restrict__ part, const float* __restrict__ ceArr,
    float* __restrict__ paucArr, float* __restrict__ validArr,
    u32* __restrict__ ctrl,      // [0]=doneCtr, [1..128]=pairCtr (zeroed)
    u32* __restrict__ gHalf,     // [2][128][128]: per-half per-class sums
    float* __restrict__ out)
{
    __shared__ u32 aB[NB], pB[NB];
    __shared__ u32 role;

    const int k  = blockIdx.x & 127;  // class
    const int h  = blockIdx.x >> 7;   // half of the partials
    const int t  = threadIdx.x;
    const int w  = t & 31;            // packed u16x2 word within class row
    const int sl = t >> 5;            // slice: 32 x 8 partials

    if (t < NB) { aB[t] = 0u; pB[t] = 0u; }
    __syncthreads();

    u32 alo = 0u, ahi = 0u, plo = 0u, phi = 0u;
    const u32* baseA = part + (size_t)(h * 256 + sl * 8) * PART_WORDS + k * 32 + w;
    const u32* baseP = part + (size_t)(h * 256 + sl * 8) * PART_WORDS + 4096 + k * 16 + (w >> 1);
    const int  psh   = 16 * (w & 1);  // byte pair within the u8x4 pos word
    #pragma unroll
    for (int b = 0; b < 8; b++) {
        const u32 qa = baseA[(size_t)b * PART_WORDS];
        const u32 qp = baseP[(size_t)b * PART_WORDS];
        alo += qa & 0xffffu;            ahi += qa >> 16;
        plo += (qp >> psh) & 0xffu;     phi += (qp >> (psh + 8)) & 0xffu;
    }
    atomicAdd(&aB[2 * w], alo); atomicAdd(&aB[2 * w + 1], ahi);
    atomicAdd(&pB[2 * w], plo); atomicAdd(&pB[2 * w + 1], phi);
    __syncthreads();

    // Publish own half-sum (agent scope -> visible across XCDs).
    if (t < 2 * NB) {
        const u32 v = (t < NB) ? aB[t] : pB[t - NB];
        __hip_atomic_store(&gHalf[(size_t)((h << 7) + k) * 128 + t], v,
                           __ATOMIC_RELAXED, __HIP_MEMORY_SCOPE_AGENT);
    }
    __syncthreads();                  // every thread's store has completed
    if (t == 0) {
        __threadfence();
        role = atomicAdd(&ctrl[1 + k], 1u);
    }
    __syncthreads();
    if (role == 0u) return;           // first arriver: data published, done

    if (t < 64) {
        const int l = t;
        const u32* oth = gHalf + (size_t)(((h ^ 1) << 7) + k) * 128;
        const u32 a = aB[63 - l] +
            __hip_atomic_load(&oth[63 - l],      __ATOMIC_RELAXED,
                              __HIP_MEMORY_SCOPE_AGENT);
        const u32 p = pB[63 - l] +
            __hip_atomic_load(&oth[64 + 63 - l], __ATOMIC_RELAXED,
                              __HIP_MEMORY_SCOPE_AGENT);

        u32 ia = a, ip = p;           // inclusive scan (descending order)
        #pragma unroll
        for (int o = 1; o < 64; o <<= 1) {
            const u32 tA = __shfl_up(ia, o);
            const u32 tP = __shfl_up(ip, o);
            if (l >= o) { ia += tA; ip += tP; }
        }
        const u32 P = __shfl(ip, 63);
        const u32 T = __shfl(ia, 63);
        const float Pm = fmaxf((float)P, 1.0f);
        const float Fm = fmaxf((float)(T - P), 1.0f);

        const int cumA = (int)(ia - a), cumP = (int)(ip - p);  // exclusive
        float contrib = 0.0f;
        const int f = (int)a - (int)p;
        if (f > 0) {
            const float fpr0 = (float)(cumA - cumP) / Fm;
            if (fpr0 < MAX_FPR) {
                const float tpr0 = (float)cumP / Pm;
                const float tpr1 = (float)(cumP + (int)p) / Pm;
                const float fpr1 = (float)(cumA - cumP + f) / Fm;
                if (fpr1 <= MAX_FPR) {
                    contrib = (fpr1 - fpr0) * 0.5f * (tpr0 + tpr1);
                } else {
                    const float tfrac = (MAX_FPR - fpr0) / (fpr1 - fpr0);
                    const float tprc  = tpr0 + tfrac * (tpr1 - tpr0);
                    contrib = (MAX_FPR - fpr0) * 0.5f * (tpr0 + tprc);
                }
            }
        }
        #pragma unroll
        for (int o = 32; o; o >>= 1) contrib += __shfl_xor(contrib, o);

        int isLast = 0;
        if (l == 0) {
            paucArr[k]  = (P > 0u) ? contrib : 0.0f;   // plain stores
            validArr[k] = (P > 0u) ? 1.0f : 0.0f;
            __threadfence();
            const u32 tk = atomicAdd(&ctrl[0], 1u);
            isLast = (tk == NUM_CLASSES - 1);
        }
        isLast = __shfl(isLast, 0);

        if (isLast) {   // all 64 lanes gather + reduce
            float s1 = 0.0f, s2 = 0.0f, s3 = 0.0f;
            #pragma unroll
            for (int i = l; i < NUM_CLASSES; i += 64) {
                s1 += __hip_atomic_load(paucArr + i,  __ATOMIC_RELAXED,
                                        __HIP_MEMORY_SCOPE_AGENT);
                s2 += __hip_atomic_load(validArr + i, __ATOMIC_RELAXED,
                                        __HIP_MEMORY_SCOPE_AGENT);
            }
            #pragma unroll
            for (int i = l; i < NBLK; i += 64) s3 += ceArr[i];  // prev kernel
            #pragma unroll
            for (int o = 32; o; o >>= 1) {
                s1 += __shfl_xor(s1, o);
                s2 += __shfl_xor(s2, o);
                s3 += __shfl_xor(s3, o);
            }
            if (l == 0) {
                const float cem  = s3 * (1.0f / (float)N_SAMPLES);
                const float pauc = s1 / fmaxf(s2, 1.0f);
                out[0] = 0.5f * cem + 0.5f * (1.0f - pauc * pauc);
            }
        }
    }
}

extern "C" void kernel_launch(void* const* d_in, const int* in_sizes, int n_in,
                              void* d_out, int out_size, void* d_ws, size_t ws_size,
                              hipStream_t stream)
{
    const float* pred = (const float*)d_in[0];
    const int*   tgt  = (const int*)d_in[1];

    char* ws = (char*)d_ws;
    u32*   part    = (u32*)ws;                          // 12.58 MB partials
    float* ceArr   = (float*)(ws + 12582912);           // 2 KB
    float* paucArr = (float*)(ws + 12582912 + 2048);    // 512 B
    float* validArr= (float*)(ws + 12582912 + 2560);    // 512 B
    u32*   ctrl    = (u32*)  (ws + 12582912 + 3072);    // 1 KB (done+pair)
    u32*   gHalf   = (u32*)  (ws + 12582912 + 4096);    // 128 KB half-sums

    // NO memset: ctrl is zeroed by fused block 0; everything else is fully
    // overwritten before being read (see kernel notes).
    fused_kernel<<<NBLK, 1024, 0, stream>>>(pred, tgt, part, ceArr, ctrl);
    pauc_reduce<<<2 * NUM_CLASSES, 1024, 0, stream>>>(part, ceArr, paucArr,
                                                      validArr, ctrl, gHalf,
                                                      (float*)d_out);
}

// Round 6
// 102.889 us; speedup vs baseline: 1.0437x; 1.0437x over previous
//
#include <hip/hip_runtime.h>
#include <math.h>

#define N_SAMPLES 131072
#define NUM_CLASSES 128
#define NB 64                 // bins (width 1/4 over s in [-14, 2])
#define MAX_FPR 0.7f          // 1 - RECALL_THRESHOLD
#define NBLK 512              // fused grid: 2 blocks/CU
#define ROWS_PER_BLK 256      // max per-bin count/block = 256 -> u16-safe
#define HP 33                 // class row pitch in LDS u32 words (32 + 1 pad)
// Partial layout per block: [0..4095] all-hist u16x2 (16 KB),
// [4096..6143] pos-hist u8x4 (8 KB). 24 KB/block -> 12.6 MB total.
#define PART_WORDS 6144

typedef unsigned int u32;

// bin(x; L) = floor((x - L + 14) * 4) clamped to [0,63]. Identical expression
// for the positive and the all histogram (same kernel, same registers).
__device__ __forceinline__ int bin_of(float x, float off /* (14-lse)*4 */) {
    int b = (int)__fmaf_rn(x, 4.0f, off);
    return min(max(b, 0), NB - 1);
}

// ---------------------------------------------------------------------------
// Fused phase 1 — proven body (verified 102.9us round 4; main loop
// byte-identical to the 104.8us round-0 kernel). NB=64, two LDS hists,
// 34 KB LDS -> 2 blocks/CU (32 waves/CU), 256 rows/block, 16 lanes/row,
// 8 cols/lane via two coalesced float4 loads, 2-deep pipeline, 4 passes.
// Pos partial packed u8x4 at writeout (12.6 MB total partials).
// Round-1 lesson: ~2M device-scope atomics = op-rate wall (+18-30us);
// streamed partials are strictly cheaper.
// Round-5 lesson: split-half reducer rendezvous eats its parallelism gain;
// total-dur deltas < ~3us are fill-noise (fills wander 77-82% peak).
// NOTHING in d_ws needs pre-zeroing:
//  - partials are fully overwritten (plain stores)
//  - ceArr[block] is a plain store
//  - doneCtr is zeroed here by block 0 (only the NEXT kernel reads it)
// ---------------------------------------------------------------------------
__global__ __launch_bounds__(1024, 8) void fused_kernel(
    const float* __restrict__ pred, const int* __restrict__ tgt,
    u32* __restrict__ part,      // [NBLK][6144]
    float* __restrict__ ceArr,   // [NBLK] plain-stored CE partials
    u32* __restrict__ doneCtr)
{
    __shared__ u32 hA[NUM_CLASSES * HP];   // all hist, u16x2  (16.9 KB)
    __shared__ u32 hP[NUM_CLASSES * HP];   // pos hist, u16x2  (16.9 KB)
    __shared__ float wsum[16];

    const int tid  = threadIdx.x;
    const int w    = tid >> 6;        // wave 0..15
    const int lane = tid & 63;
    const int j    = lane & 15;       // lane within row
    const int rs   = lane >> 4;       // row sub-index 0..3

    for (int i = tid; i < NUM_CLASSES * HP; i += 1024) { hA[i] = 0u; hP[i] = 0u; }
    if (blockIdx.x == 0 && tid == 0) *doneCtr = 0u;
    __syncthreads();

    const int rowBase = blockIdx.x * ROWS_PER_BLK + w * 4 + rs;
    float acc_lse = 0.0f, acc_xt = 0.0f, acc_sx = 0.0f;

    // 2-deep pipeline over 4 passes (row stride 64 per pass)
    const float* r0p = pred + (size_t)rowBase * 128;
    float4 a0 = *(const float4*)(r0p + j * 4);
    float4 a1 = *(const float4*)(r0p + 64 + j * 4);
    int    ta = tgt[rowBase];
    const float* r1p = r0p + (size_t)64 * 128;
    float4 c0 = *(const float4*)(r1p + j * 4);
    float4 c1 = *(const float4*)(r1p + 64 + j * 4);
    int    tb = tgt[rowBase + 64];

    #pragma unroll
    for (int p = 0; p < 4; p++) {
        float4 n0, n1; int tn = 0;
        if (p < 2) {
            const float* rn = pred + (size_t)(rowBase + (p + 2) * 64) * 128;
            n0 = *(const float4*)(rn + j * 4);
            n1 = *(const float4*)(rn + 64 + j * 4);
            tn = tgt[rowBase + (p + 2) * 64];
        }

        float e = __expf(a0.x) + __expf(a0.y) + __expf(a0.z) + __expf(a0.w)
                + __expf(a1.x) + __expf(a1.y) + __expf(a1.z) + __expf(a1.w);
        #pragma unroll
        for (int o = 1; o < 16; o <<= 1) e += __shfl_xor(e, o);
        const float lse = __logf(e);
        const float off = (14.0f - lse) * 4.0f;

        const float xv[8] = {a0.x, a0.y, a0.z, a0.w, a1.x, a1.y, a1.z, a1.w};
        #pragma unroll
        for (int q = 0; q < 8; q++) {
            const int c = (q < 4) ? (j * 4 + q) : (64 + j * 4 + (q - 4));
            const int b = bin_of(xv[q], off);
            const int word = ((b >> 1) + j) & 31;       // swizzle: 16 banks
            atomicAdd(&hA[c * HP + word], (b & 1) ? 65536u : 1u);
        }

        acc_sx  += (xv[0] + xv[1] + xv[2] + xv[3])
                 + (xv[4] + xv[5] + xv[6] + xv[7]);
        acc_lse += lse * 0.0625f;     // 16 lanes/row each add lse/16

        {   // exactly one of the row's 16 lanes owns the target column
            const int t = ta;
            float xt; bool hit = false;
            if ((t >> 2) == j)                        { xt = xv[t & 3];       hit = true; }
            else if (t >= 64 && ((t - 64) >> 2) == j) { xt = xv[4 + (t & 3)]; hit = true; }
            if (hit) {
                acc_xt += xt;
                const int bp = bin_of(xt, off);
                atomicAdd(&hP[t * HP + (((bp >> 1) + j) & 31)],
                          (bp & 1) ? 65536u : 1u);
            }
        }

        a0 = c0; a1 = c1; ta = tb;
        c0 = n0; c1 = n1; tb = tn;
    }

    // CE partial: sum(lse) - 0.9*sum(x_t) - (0.1/128)*sum(x)
    float ce = acc_lse - 0.9f * acc_xt - (0.1f / 128.0f) * acc_sx;
    #pragma unroll
    for (int o = 32; o; o >>= 1) ce += __shfl_xor(ce, o);
    if (lane == 0) wsum[w] = ce;
    __syncthreads();
    if (tid == 0) {
        float s = 0.0f;
        #pragma unroll
        for (int i = 0; i < 16; i++) s += wsum[i];
        ceArr[blockIdx.x] = s;       // plain store, no init needed
    }

    // un-rotating writeout. All-hist: linear i = c*32 + bw, u16x2 unchanged.
    u32* outp = part + (size_t)blockIdx.x * PART_WORDS;
    for (int i = tid; i < 4096; i += 1024) {
        const int c = i >> 5, bw = i & 31;
        const int src = c * HP + ((bw + ((c >> 2) & 15)) & 31);
        outp[i] = hA[src];
    }
    // Pos-hist: pack 4 bins/u32 (u8 each). Word w4 of class c covers bins
    // 4*w4 .. 4*w4+3, i.e. LDS u16x2 words (2*w4 + jc)&31 and (2*w4+1 + jc)&31.
    for (int i = tid; i < 2048; i += 1024) {
        const int c  = i >> 4, w4 = i & 15;
        const int jc = (c >> 2) & 15;
        const u32 lo = hP[c * HP + (((2 * w4)     + jc) & 31)]; // bins 4w4,4w4+1
        const u32 hi = hP[c * HP + (((2 * w4 + 1) + jc) & 31)]; // bins 4w4+2,+3
        const u32 b0 = min(lo & 0xffffu, 255u);
        const u32 b1 = min(lo >> 16,     255u);
        const u32 b2 = min(hi & 0xffffu, 255u);
        const u32 b3 = min(hi >> 16,     255u);
        outp[4096 + i] = b0 | (b1 << 8) | (b2 << 16) | (b3 << 24);
    }
}

// ---------------------------------------------------------------------------
// Reducer + finalize (round-4 verified version): one block per class, 1024
// threads for memory-level parallelism on the latency-bound strided partial
// reads. Thread t: word w = t&31 (bins 2w, 2w+1), slice sl = t>>5 covers 16
// of the 512 partials (coalesced, 8-deep MLP). Pos hist unpacks u8x4: lanes
// 2k,2k+1 share pos word w>>1 (broadcast). LDS-atomic merge into 64 u32 bins
// each, then wave 0 (t<64) does the scan + clipped trapezoidal pAUC.
// Ticket / fence / agent-scope-load finalize identical to round-0 verified.
// ---------------------------------------------------------------------------
__global__ __launch_bounds__(1024) void pauc_reduce(
    const u32* __restrict__ part, const float* __restrict__ ceArr,
    float* __restrict__ paucArr, float* __restrict__ validArr,
    u32* __restrict__ doneCtr, float* __restrict__ out)
{
    __shared__ u32 aB[NB], pB[NB];

    const int k  = blockIdx.x;
    const int t  = threadIdx.x;
    const int w  = t & 31;            // packed u16x2 word within class row
    const int sl = t >> 5;            // slice of the partials (32 x 16)

    if (t < NB) { aB[t] = 0u; pB[t] = 0u; }
    __syncthreads();

    u32 alo = 0u, ahi = 0u, plo = 0u, phi = 0u;
    const u32* baseA = part + (size_t)(sl * 16) * PART_WORDS + k * 32 + w;
    const u32* baseP = part + (size_t)(sl * 16) * PART_WORDS + 4096 + k * 16 + (w >> 1);
    const int  psh   = 16 * (w & 1);  // byte pair within the u8x4 pos word
    #pragma unroll 8
    for (int b = 0; b < 16; b++) {
        const u32 qa = baseA[(size_t)b * PART_WORDS];
        const u32 qp = baseP[(size_t)b * PART_WORDS];
        alo += qa & 0xffffu;            ahi += qa >> 16;
        plo += (qp >> psh) & 0xffu;     phi += (qp >> (psh + 8)) & 0xffu;
    }
    atomicAdd(&aB[2 * w], alo); atomicAdd(&aB[2 * w + 1], ahi);
    atomicAdd(&pB[2 * w], plo); atomicAdd(&pB[2 * w + 1], phi);
    __syncthreads();

    if (t < 64) {
        const int l = t;
        const u32 a = aB[63 - l];     // lane l owns DESCENDING bin 63-l
        const u32 p = pB[63 - l];

        u32 ia = a, ip = p;           // inclusive scan (descending order)
        #pragma unroll
        for (int o = 1; o < 64; o <<= 1) {
            const u32 tA = __shfl_up(ia, o);
            const u32 tP = __shfl_up(ip, o);
            if (l >= o) { ia += tA; ip += tP; }
        }
        const u32 P = __shfl(ip, 63);
        const u32 T = __shfl(ia, 63);
        const float Pm = fmaxf((float)P, 1.0f);
        const float Fm = fmaxf((float)(T - P), 1.0f);

        const int cumA = (int)(ia - a), cumP = (int)(ip - p);  // exclusive
        float contrib = 0.0f;
        const int f = (int)a - (int)p;
        if (f > 0) {
            const float fpr0 = (float)(cumA - cumP) / Fm;
            if (fpr0 < MAX_FPR) {
                const float tpr0 = (float)cumP / Pm;
                const float tpr1 = (float)(cumP + (int)p) / Pm;
                const float fpr1 = (float)(cumA - cumP + f) / Fm;
                if (fpr1 <= MAX_FPR) {
                    contrib = (fpr1 - fpr0) * 0.5f * (tpr0 + tpr1);
                } else {
                    const float tfrac = (MAX_FPR - fpr0) / (fpr1 - fpr0);
                    const float tprc  = tpr0 + tfrac * (tpr1 - tpr0);
                    contrib = (MAX_FPR - fpr0) * 0.5f * (tpr0 + tprc);
                }
            }
        }
        #pragma unroll
        for (int o = 32; o; o >>= 1) contrib += __shfl_xor(contrib, o);

        int isLast = 0;
        if (l == 0) {
            paucArr[k]  = (P > 0u) ? contrib : 0.0f;   // plain stores
            validArr[k] = (P > 0u) ? 1.0f : 0.0f;
            __threadfence();
            const u32 tk = atomicAdd(doneCtr, 1u);
            isLast = (tk == NUM_CLASSES - 1);
        }
        isLast = __shfl(isLast, 0);

        if (isLast) {   // all 64 lanes gather + reduce
            float s1 = 0.0f, s2 = 0.0f, s3 = 0.0f;
            #pragma unroll
            for (int i = l; i < NUM_CLASSES; i += 64) {
                s1 += __hip_atomic_load(paucArr + i,  __ATOMIC_RELAXED,
                                        __HIP_MEMORY_SCOPE_AGENT);
                s2 += __hip_atomic_load(validArr + i, __ATOMIC_RELAXED,
                                        __HIP_MEMORY_SCOPE_AGENT);
            }
            #pragma unroll
            for (int i = l; i < NBLK; i += 64) s3 += ceArr[i];  // prev kernel
            #pragma unroll
            for (int o = 32; o; o >>= 1) {
                s1 += __shfl_xor(s1, o);
                s2 += __shfl_xor(s2, o);
                s3 += __shfl_xor(s3, o);
            }
            if (l == 0) {
                const float cem  = s3 * (1.0f / (float)N_SAMPLES);
                const float pauc = s1 / fmaxf(s2, 1.0f);
                out[0] = 0.5f * cem + 0.5f * (1.0f - pauc * pauc);
            }
        }
    }
}

extern "C" void kernel_launch(void* const* d_in, const int* in_sizes, int n_in,
                              void* d_out, int out_size, void* d_ws, size_t ws_size,
                              hipStream_t stream)
{
    const float* pred = (const float*)d_in[0];
    const int*   tgt  = (const int*)d_in[1];

    char* ws = (char*)d_ws;
    u32*   part    = (u32*)ws;                          // 12.58 MB partials
    float* ceArr   = (float*)(ws + 12582912);           // 2 KB
    float* paucArr = (float*)(ws + 12582912 + 2048);    // 512 B
    float* validArr= (float*)(ws + 12582912 + 2560);    // 512 B
    u32*   doneCtr = (u32*)  (ws + 12582912 + 3072);    // 4 B

    // NO memset: nothing in d_ws requires initialization (see kernel notes).
    fused_kernel<<<NBLK, 1024, 0, stream>>>(pred, tgt, part, ceArr, doneCtr);
    pauc_reduce<<<NUM_CLASSES, 1024, 0, stream>>>(part, ceArr, paucArr, validArr,
                                                  doneCtr, (float*)d_out);
}